// Round 1
// baseline (1152.360 us; speedup 1.0000x reference)
//
#include <hip/hip_runtime.h>

// BPR loss with negative sampling, B=64, T=200, V=20000, S=1.
// loss = sum_b [ -(1/L_b^2) * sum_{i<L,j<L} log_sigmoid(out[b,i,lab[b,j]] - out[b,i,neg[b,j]]) ]

#define BB 64
#define TT 200
#define VV 20000

__global__ void bpr_zero_kernel(float* out) { out[0] = 0.0f; }

__global__ __launch_bounds__(64) void bpr_loss_kernel(
    const float* __restrict__ output,
    const int*   __restrict__ labels,
    const int*   __restrict__ x_lens,
    const int*   __restrict__ neg_ids,
    float*       __restrict__ result)
{
    const int blk = blockIdx.x;
    const int b = blk / TT;
    const int i = blk - b * TT;
    const int L = x_lens[b];
    if (i >= L) return;

    const float* __restrict__ row = output + ((size_t)b * TT + i) * VV;
    const int*   __restrict__ lab = labels  + b * TT;
    const int*   __restrict__ neg = neg_ids + b * TT;

    const int lane = threadIdx.x;
    float sum = 0.0f;
    for (int j = lane; j < L; j += 64) {
        const int cp = lab[j];
        const int cn = neg[j];
        const float xp = row[cp];
        const float xn = row[cn];
        const float d  = xp - xn;
        // stable log_sigmoid(d) = min(d,0) - log1p(exp(-|d|))
        const float ls = fminf(d, 0.0f) - log1pf(__expf(-fabsf(d)));
        sum += ls;
    }

    // wave64 butterfly reduction
    #pragma unroll
    for (int off = 32; off > 0; off >>= 1)
        sum += __shfl_down(sum, off, 64);

    if (lane == 0) {
        const float Lf = (float)L;
        atomicAdd(result, -sum / (Lf * Lf));   // S == 1
    }
}

extern "C" void kernel_launch(void* const* d_in, const int* in_sizes, int n_in,
                              void* d_out, int out_size, void* d_ws, size_t ws_size,
                              hipStream_t stream) {
    const float* output  = (const float*)d_in[0];
    const int*   labels  = (const int*)d_in[1];
    const int*   x_lens  = (const int*)d_in[2];
    // d_in[3] = uids (unused by the reference computation)
    const int*   neg_ids = (const int*)d_in[4];
    float* result = (float*)d_out;

    bpr_zero_kernel<<<1, 1, 0, stream>>>(result);
    bpr_loss_kernel<<<BB * TT, 64, 0, stream>>>(output, labels, x_lens, neg_ids, result);
}

// Round 2
// 1110.860 us; speedup vs baseline: 1.0374x; 1.0374x over previous
//
#include <hip/hip_runtime.h>

// BPR loss with negative sampling, B=64, T=200, V=20000, S=1.
// loss = sum_b [ -(1/L_b^2) * sum_{i<L,j<L} log_sigmoid(out[b,i,lab[b,j]] - out[b,i,neg[b,j]]) ]
//
// R2: removed single-address device atomicAdd (6400 serialized cross-XCD RMWs,
// ~150 us) -> per-block partials in d_ws + one-block tree reduce.

#define BB 64
#define TT 200
#define VV 20000
#define NBLK (BB * TT)

__global__ __launch_bounds__(64) void bpr_partial_kernel(
    const float* __restrict__ output,
    const int*   __restrict__ labels,
    const int*   __restrict__ x_lens,
    const int*   __restrict__ neg_ids,
    float*       __restrict__ partial)
{
    const int blk = blockIdx.x;
    const int b = blk / TT;
    const int i = blk - b * TT;
    const int L = x_lens[b];
    const int lane = threadIdx.x;

    float sum = 0.0f;
    if (i < L) {
        const float* __restrict__ row = output + ((size_t)b * TT + i) * VV;
        const int*   __restrict__ lab = labels  + b * TT;
        const int*   __restrict__ neg = neg_ids + b * TT;
        for (int j = lane; j < L; j += 64) {
            const float xp = row[lab[j]];
            const float xn = row[neg[j]];
            const float d  = xp - xn;
            // stable log_sigmoid(d) = min(d,0) - log1p(exp(-|d|))
            sum += fminf(d, 0.0f) - log1pf(__expf(-fabsf(d)));
        }
    }

    // wave64 butterfly reduction
    #pragma unroll
    for (int off = 32; off > 0; off >>= 1)
        sum += __shfl_down(sum, off, 64);

    if (lane == 0) {
        const float Lf = (float)L;          // L >= 1 always
        partial[blk] = -sum / (Lf * Lf);    // 0 when i >= L (ws is poisoned -> must write)
    }
}

__global__ __launch_bounds__(1024) void bpr_reduce_kernel(
    const float* __restrict__ partial, float* __restrict__ out)
{
    float s = 0.0f;
    for (int k = threadIdx.x; k < NBLK; k += 1024)
        s += partial[k];

    __shared__ float wsum[16];
    #pragma unroll
    for (int off = 32; off > 0; off >>= 1)
        s += __shfl_down(s, off, 64);
    if ((threadIdx.x & 63) == 0) wsum[threadIdx.x >> 6] = s;
    __syncthreads();

    if (threadIdx.x < 64) {
        float v = (threadIdx.x < 16) ? wsum[threadIdx.x] : 0.0f;
        #pragma unroll
        for (int off = 32; off > 0; off >>= 1)
            v += __shfl_down(v, off, 64);
        if (threadIdx.x == 0) out[0] = v;
    }
}

extern "C" void kernel_launch(void* const* d_in, const int* in_sizes, int n_in,
                              void* d_out, int out_size, void* d_ws, size_t ws_size,
                              hipStream_t stream) {
    const float* output  = (const float*)d_in[0];
    const int*   labels  = (const int*)d_in[1];
    const int*   x_lens  = (const int*)d_in[2];
    // d_in[3] = uids (unused by the reference computation)
    const int*   neg_ids = (const int*)d_in[4];
    float* partial = (float*)d_ws;          // NBLK floats = 51.2 KB
    float* result  = (float*)d_out;

    bpr_partial_kernel<<<NBLK, 64, 0, stream>>>(output, labels, x_lens, neg_ids, partial);
    bpr_reduce_kernel<<<1, 1024, 0, stream>>>(partial, result);
}